// Round 1
// baseline (152.300 us; speedup 1.0000x reference)
//
#include <hip/hip_runtime.h>

// Problem constants (src: [1,2,160,192,224] f32, flow: [1,3,160,192,224] f32)
constexpr int D = 160;
constexpr int H = 192;
constexpr int W = 224;
constexpr int N = D * H * W;  // 6,881,280 voxels (= 26880 * 256 exactly)

__global__ __launch_bounds__(256) void warp3d_kernel(
    const float* __restrict__ src,
    const float* __restrict__ flow,
    float* __restrict__ out)
{
    const int idx = blockIdx.x * 256 + threadIdx.x;
    if (idx >= N) return;

    // decompose idx -> (z, y, x); compiler uses magic-multiply for const div
    const int x = idx % W;
    const int t = idx / W;
    const int y = t % H;
    const int z = t / H;

    // sample position = grid + flow  (flow channel i displaces spatial dim i: z,y,x)
    const float pz = flow[idx]         + (float)z;
    const float py = flow[N + idx]     + (float)y;
    const float px = flow[2 * N + idx] + (float)x;

    const float z0f = floorf(pz), y0f = floorf(py), x0f = floorf(px);
    const float fz = pz - z0f, fy = py - y0f, fx = px - x0f;
    const int z0 = (int)z0f, y0 = (int)y0f, x0 = (int)x0f;

    const float wz[2] = {1.0f - fz, fz};
    const float wy[2] = {1.0f - fy, fy};
    const float wx[2] = {1.0f - fx, fx};

    float acc0 = 0.0f;  // channel 0
    float acc1 = 0.0f;  // channel 1

    #pragma unroll
    for (int dz = 0; dz < 2; ++dz) {
        const int zi = z0 + dz;
        const bool vz = (unsigned)zi < (unsigned)D;
        const int zc = min(max(zi, 0), D - 1);
        #pragma unroll
        for (int dy = 0; dy < 2; ++dy) {
            const int yi = y0 + dy;
            const bool vy = (unsigned)yi < (unsigned)H;
            const int yc = min(max(yi, 0), H - 1);
            const int rowbase = (zc * H + yc) * W;
            const float wzy = wz[dz] * wy[dy];
            #pragma unroll
            for (int dx = 0; dx < 2; ++dx) {
                const int xi = x0 + dx;
                const bool vx = (unsigned)xi < (unsigned)W;
                const int xc = min(max(xi, 0), W - 1);
                const int lin = rowbase + xc;
                // zeros padding: zero the WEIGHT (index stays clamped in-bounds,
                // so loads are always safe and there is no divergent branch)
                const float w = (vz && vy && vx) ? (wzy * wx[dx]) : 0.0f;
                acc0 = fmaf(w, src[lin],     acc0);
                acc1 = fmaf(w, src[N + lin], acc1);
            }
        }
    }

    out[idx]     = acc0;
    out[N + idx] = acc1;
}

extern "C" void kernel_launch(void* const* d_in, const int* in_sizes, int n_in,
                              void* d_out, int out_size, void* d_ws, size_t ws_size,
                              hipStream_t stream) {
    const float* src  = (const float*)d_in[0];  // [1,2,D,H,W]
    const float* flow = (const float*)d_in[1];  // [1,3,D,H,W]
    float* out = (float*)d_out;                 // [1,2,D,H,W]

    const int blocks = (N + 255) / 256;  // 26880
    warp3d_kernel<<<blocks, 256, 0, stream>>>(src, flow, out);
}

// Round 2
// 116.637 us; speedup vs baseline: 1.3058x; 1.3058x over previous
//
#include <hip/hip_runtime.h>

// src: [1,2,160,192,224] f32, flow: [1,3,160,192,224] f32, out: [1,2,160,192,224] f32
constexpr int D = 160;
constexpr int H = 192;
constexpr int W = 224;
constexpr int N = D * H * W;  // 6,881,280 = 26880 * 256 exactly

typedef float f2v __attribute__((ext_vector_type(2)));

// 8-byte load at a 4-byte-aligned address. memcpy keeps it legal; gfx950
// supports unaligned global access, so the backend can emit global_load_dwordx2.
__device__ __forceinline__ f2v ld2(const float* __restrict__ p) {
    f2v v;
    __builtin_memcpy(&v, p, sizeof(v));
    return v;
}

__global__ __launch_bounds__(256) void warp3d_kernel(
    const float* __restrict__ src,
    const float* __restrict__ flow,
    float* __restrict__ out)
{
    const int idx = blockIdx.x * 256 + threadIdx.x;  // grid covers N exactly

    const int x = idx % W;
    const int t = idx / W;
    const int y = t % H;
    const int z = t / H;

    // sample position = grid + flow (flow channel i displaces spatial dim i: z,y,x)
    const float pz = flow[idx]         + (float)z;
    const float py = flow[N + idx]     + (float)y;
    const float px = flow[2 * N + idx] + (float)x;

    const float z0f = floorf(pz), y0f = floorf(py), x0f = floorf(px);
    const float fz = pz - z0f, fy = py - y0f, fx = px - x0f;
    const int z0 = (int)z0f, y0 = (int)y0f, x0 = (int)x0f;

    // zeros-padding folded into separable per-axis weights
    const float wz0 = ((unsigned)z0       < (unsigned)D) ? (1.0f - fz) : 0.0f;
    const float wz1 = ((unsigned)(z0 + 1) < (unsigned)D) ? fz          : 0.0f;
    const float wy0 = ((unsigned)y0       < (unsigned)H) ? (1.0f - fy) : 0.0f;
    const float wy1 = ((unsigned)(y0 + 1) < (unsigned)H) ? fy          : 0.0f;
    const float wx0 = ((unsigned)x0       < (unsigned)W) ? (1.0f - fx) : 0.0f;
    const float wx1 = ((unsigned)(x0 + 1) < (unsigned)W) ? fx          : 0.0f;

    // clamped corner indices
    const int zc0 = min(max(z0, 0), D - 1), zc1 = min(max(z0 + 1, 0), D - 1);
    const int yc0 = min(max(y0, 0), H - 1), yc1 = min(max(y0 + 1, 0), H - 1);
    const int xc0 = min(max(x0, 0), W - 1);
    const int xc1 = min(max(x0 + 1, 0), W - 1);
    // 2-wide x base, always fully in-bounds; o0/o1 select within the pair.
    // Invalid corners have zero weight, so their (clamped) value is harmless.
    const int xb = min(xc0, W - 2);
    const int o0 = xc0 - xb;   // 0 or 1
    const int o1 = xc1 - xb;   // 0 or 1

    const int r00 = (zc0 * H + yc0) * W + xb;
    const int r01 = (zc0 * H + yc1) * W + xb;
    const int r10 = (zc1 * H + yc0) * W + xb;
    const int r11 = (zc1 * H + yc1) * W + xb;

    // Issue all 8 scattered loads up-front (independent -> one vmcnt wait).
    const f2v a00 = ld2(src + r00);
    const f2v a01 = ld2(src + r01);
    const f2v a10 = ld2(src + r10);
    const f2v a11 = ld2(src + r11);
    const f2v b00 = ld2(src + N + r00);
    const f2v b01 = ld2(src + N + r01);
    const f2v b10 = ld2(src + N + r10);
    const f2v b11 = ld2(src + N + r11);

    const float w00 = wz0 * wy0;
    const float w01 = wz0 * wy1;
    const float w10 = wz1 * wy0;
    const float w11 = wz1 * wy1;

    const float acc0 = w00 * (wx0 * a00[o0] + wx1 * a00[o1])
                     + w01 * (wx0 * a01[o0] + wx1 * a01[o1])
                     + w10 * (wx0 * a10[o0] + wx1 * a10[o1])
                     + w11 * (wx0 * a11[o0] + wx1 * a11[o1]);
    const float acc1 = w00 * (wx0 * b00[o0] + wx1 * b00[o1])
                     + w01 * (wx0 * b01[o0] + wx1 * b01[o1])
                     + w10 * (wx0 * b10[o0] + wx1 * b10[o1])
                     + w11 * (wx0 * b11[o0] + wx1 * b11[o1]);

    out[idx]     = acc0;
    out[N + idx] = acc1;
}

extern "C" void kernel_launch(void* const* d_in, const int* in_sizes, int n_in,
                              void* d_out, int out_size, void* d_ws, size_t ws_size,
                              hipStream_t stream) {
    const float* src  = (const float*)d_in[0];
    const float* flow = (const float*)d_in[1];
    float* out = (float*)d_out;

    warp3d_kernel<<<N / 256, 256, 0, stream>>>(src, flow, out);
}